// Round 8
// baseline (23.656 us; speedup 1.0000x reference)
//
#include <hip/hip_runtime.h>
#include <math.h>

// Geometry (fixed by the reference).
#define HS    2048            // hidden size (output columns)
#define DIN   2048            // input dim (reduction length)
#define RPS   16              // rows per slab
#define NSLAB (DIN / RPS)     // 128 slabs per matrix
#define NBLK1 1024            // 4 mats x 128 slabs x 2 column halves
#define NBLK2 64              // stage-2 blocks

// ---------------------------------------------------------------------------
// Algebra: cell = f*c0 + dot(i,c); dot(i,c) is a scalar broadcast and the
// mean/std normalization cancels constant shifts, so
//   h = o * tanh((f*c0 - mean(f*c0)) / (std(f*c0, ddof=1) + 1e-5)).
// The i and c gates (w_xi, w_hi, w_xc, w_hc, b_i, b_c) are dead.
//
// Stage 1: slab-streaming partial GEMV with INTERLEAVED row mapping.
//   Block b: mat = b>>8, rem = b&255, slab = rem>>1, ch = rem&1 (1024-col
//   half). Slab s covers rows {s + 128k, k=0..15} (stride-128 interleave)
//   instead of blocked rows {16s..16s+15}: when the grid is at step k, ALL
//   blocks together read the contiguous row band [128k, 128k+128) of all 4
//   matrices — a dense ~4 MB window sweeping memory sequentially (copy-
//   µbench-like global order), instead of 1024 scattered 8 KB-strided
//   streams. Same traffic, same instruction mix as r6; ONLY address order
//   changes. Thread t owns fixed col quad ch*1024 + t*4; 16-row reduction
//   in registers; one coalesced 4 KB partial-row store per block. zp total
//   4 MB, pure overwrite (poison-proof), no atomics.
// Stage-2 sums over all slabs per gate, so it is agnostic to the slab->row
// mapping (unchanged from r6).
// ---------------------------------------------------------------------------
__global__ __launch_bounds__(256) void gemv_slab(
        const float* __restrict__ x,    const float* __restrict__ h0,
        const float* __restrict__ w_xf, const float* __restrict__ w_hf,
        const float* __restrict__ w_xo, const float* __restrict__ w_ho,
        float* __restrict__ zp /* [NBLK1][1024] */) {
    const int b    = blockIdx.x;
    const int t    = threadIdx.x;
    const int mat  = b >> 8;                 // 0:w_xf 1:w_hf 2:w_xo 3:w_ho
    const int rem  = b & 255;
    const int slab = rem >> 1;
    const int ch   = rem & 1;

    const float* W   = (mat == 0) ? w_xf : (mat == 1) ? w_hf
                     : (mat == 2) ? w_xo : w_ho;
    const float* vec = (mat & 1) ? h0 : x;

    // rows: slab + 128k, k = 0..15
    const float* wp = W + (size_t)slab * HS + ch * 1024 + t * 4;

    float4 a0 = make_float4(0.f, 0.f, 0.f, 0.f);
    float4 a1 = make_float4(0.f, 0.f, 0.f, 0.f);
    float4 a2 = make_float4(0.f, 0.f, 0.f, 0.f);
    float4 a3 = make_float4(0.f, 0.f, 0.f, 0.f);
#pragma unroll
    for (int k = 0; k < RPS; k += 4) {
        const float s0 = vec[slab + ((k + 0) << 7)];   // block-uniform
        const float s1 = vec[slab + ((k + 1) << 7)];
        const float s2 = vec[slab + ((k + 2) << 7)];
        const float s3 = vec[slab + ((k + 3) << 7)];
        const float4 w0 = *reinterpret_cast<const float4*>(wp + ((size_t)(k + 0) << 18));
        const float4 w1 = *reinterpret_cast<const float4*>(wp + ((size_t)(k + 1) << 18));
        const float4 w2 = *reinterpret_cast<const float4*>(wp + ((size_t)(k + 2) << 18));
        const float4 w3 = *reinterpret_cast<const float4*>(wp + ((size_t)(k + 3) << 18));
        a0.x = fmaf(s0, w0.x, a0.x);  a0.y = fmaf(s0, w0.y, a0.y);
        a0.z = fmaf(s0, w0.z, a0.z);  a0.w = fmaf(s0, w0.w, a0.w);
        a1.x = fmaf(s1, w1.x, a1.x);  a1.y = fmaf(s1, w1.y, a1.y);
        a1.z = fmaf(s1, w1.z, a1.z);  a1.w = fmaf(s1, w1.w, a1.w);
        a2.x = fmaf(s2, w2.x, a2.x);  a2.y = fmaf(s2, w2.y, a2.y);
        a2.z = fmaf(s2, w2.z, a2.z);  a2.w = fmaf(s2, w2.w, a2.w);
        a3.x = fmaf(s3, w3.x, a3.x);  a3.y = fmaf(s3, w3.y, a3.y);
        a3.z = fmaf(s3, w3.z, a3.z);  a3.w = fmaf(s3, w3.w, a3.w);
    }
    float4 r4;
    r4.x = (a0.x + a1.x) + (a2.x + a3.x);
    r4.y = (a0.y + a1.y) + (a2.y + a3.y);
    r4.z = (a0.z + a1.z) + (a2.z + a3.z);
    r4.w = (a0.w + a1.w) + (a2.w + a3.w);
    reinterpret_cast<float4*>(zp + (size_t)b * 1024)[t] = r4;
}

// ---------------------------------------------------------------------------
// Stage 2 (unchanged from r6; zp layout identical): reduce 256 slab-partials
// per (gate, column) with float4 loads, sigmoid, then last-block ticket ->
// mean/std normalize -> output. atomicInc-wrap ticket selects exactly one
// block per call for ANY initial counter value (0xAA poison ok).
// ---------------------------------------------------------------------------
__global__ __launch_bounds__(256) void reduce_fin(
        const float* __restrict__ zp,
        const float* __restrict__ b_f, const float* __restrict__ b_o,
        const float* __restrict__ c0,  float* __restrict__ out,
        float* __restrict__ vbuf, float* __restrict__ obuf,
        unsigned* __restrict__ cnt) {
    const int t  = threadIdx.x;
    const int g  = blockIdx.x >> 5;          // 0 = f, 1 = o
    const int cg = blockIdx.x & 31;          // 64-col group
    const int fg = t & 15;                   // float4 quad within group
    const int ph = t >> 4;                   // slab phase 0..15

    __shared__ float4 part[4][16];
    __shared__ unsigned lastFlag;

    const int ch = cg >> 4;                  // column half of this group
    const int cw = (cg & 15) * 64 + fg * 4;  // offset within the half

    float4 acc0 = make_float4(0.f, 0.f, 0.f, 0.f);
    float4 acc1 = make_float4(0.f, 0.f, 0.f, 0.f);
#pragma unroll
    for (int k = 0; k < 8; ++k) {
        const int slab = ph + (k << 4);
#pragma unroll
        for (int m = 0; m < 2; ++m) {
            const int rr = ((g * 2 + m) * NSLAB + slab) * 2 + ch;
            const float4 p = *reinterpret_cast<const float4*>(
                zp + (size_t)rr * 1024 + cw);
            float4& a = m ? acc1 : acc0;
            a.x += p.x;  a.y += p.y;  a.z += p.z;  a.w += p.w;
        }
    }
    float4 s4;
    s4.x = acc0.x + acc1.x;  s4.y = acc0.y + acc1.y;
    s4.z = acc0.z + acc1.z;  s4.w = acc0.w + acc1.w;

    // reduce the 4 in-wave phases (lanes l, l^16, l^32 hold adjacent ph)
#pragma unroll
    for (int m = 16; m <= 32; m <<= 1) {
        s4.x += __shfl_xor(s4.x, m);
        s4.y += __shfl_xor(s4.y, m);
        s4.z += __shfl_xor(s4.z, m);
        s4.w += __shfl_xor(s4.w, m);
    }
    if ((t & 63) < 16) part[t >> 6][fg] = s4;
    __syncthreads();

    if (t < 16) {
        float4 z;
        z.x = (part[0][t].x + part[1][t].x) + (part[2][t].x + part[3][t].x);
        z.y = (part[0][t].y + part[1][t].y) + (part[2][t].y + part[3][t].y);
        z.z = (part[0][t].z + part[1][t].z) + (part[2][t].z + part[3][t].z);
        z.w = (part[0][t].w + part[1][t].w) + (part[2][t].w + part[3][t].w);
        const int col = cg * 64 + t * 4;
        if (g == 0) {
            const float4 bf = *reinterpret_cast<const float4*>(b_f + col);
            const float4 cv = *reinterpret_cast<const float4*>(c0 + col);
            float4 r;
            r.x = cv.x / (1.f + expf(-(z.x + bf.x)));
            r.y = cv.y / (1.f + expf(-(z.y + bf.y)));
            r.z = cv.z / (1.f + expf(-(z.z + bf.z)));
            r.w = cv.w / (1.f + expf(-(z.w + bf.w)));
            *reinterpret_cast<float4*>(vbuf + col) = r;   // v = sig(zf)*c0
        } else {
            const float4 bo = *reinterpret_cast<const float4*>(b_o + col);
            float4 r;
            r.x = 1.f / (1.f + expf(-(z.x + bo.x)));
            r.y = 1.f / (1.f + expf(-(z.y + bo.y)));
            r.z = 1.f / (1.f + expf(-(z.z + bo.z)));
            r.w = 1.f / (1.f + expf(-(z.w + bo.w)));
            *reinterpret_cast<float4*>(obuf + col) = r;   // o gate
        }
    }
    __syncthreads();

    // ---- last-block ticket (device scope; robust to any initial cnt) ----
    if (t == 0) {
        __threadfence();                          // release vbuf/obuf writes
        const unsigned old = atomicInc(cnt, NBLK2 - 1u);
        lastFlag = (old == NBLK2 - 2u);           // exactly one block per call
    }
    __syncthreads();
    if (!lastFlag) return;
    __threadfence();                              // acquire

    // ---- finalize: h = o * tanh((v - mean) / (std_ddof1 + 1e-5)) ----
    const int lane = t & 63;
    const int wv   = t >> 6;
    __shared__ float red[2][4];

    float v[8], og[8];
    float lsum = 0.f;
#pragma unroll
    for (int e = 0; e < 8; ++e) {
        const int j = t * 8 + e;
        v[e]  = vbuf[j];
        og[e] = obuf[j];
        lsum += v[e];
    }
#pragma unroll
    for (int s = 32; s > 0; s >>= 1) lsum += __shfl_down(lsum, s);
    if (lane == 0) red[0][wv] = lsum;
    __syncthreads();
    const float mean = (red[0][0] + red[0][1] + red[0][2] + red[0][3]) * (1.f / 2048.f);

    float lss = 0.f;
#pragma unroll
    for (int e = 0; e < 8; ++e) {
        const float d = v[e] - mean;
        lss += d * d;
    }
#pragma unroll
    for (int s = 32; s > 0; s >>= 1) lss += __shfl_down(lss, s);
    if (lane == 0) red[1][wv] = lss;
    __syncthreads();
    const float var = (red[1][0] + red[1][1] + red[1][2] + red[1][3]) * (1.f / 2047.f);
    const float inv = 1.f / (sqrtf(var) + 1e-5f);

#pragma unroll
    for (int e = 0; e < 8; ++e) {
        const int j = t * 8 + e;
        out[j] = og[e] * tanhf((v[e] - mean) * inv);
    }
}

extern "C" void kernel_launch(void* const* d_in, const int* in_sizes, int n_in,
                              void* d_out, int out_size, void* d_ws, size_t ws_size,
                              hipStream_t stream) {
    // setup_inputs order:
    // 0:x 1:w_xi 2:w_xf 3:w_xo 4:w_xc 5:w_hi 6:w_hf 7:w_ho 8:w_hc
    // 9:b_i 10:b_f 11:b_o 12:b_c 13:h0 14:c0
    const float* x    = (const float*)d_in[0];
    const float* w_xf = (const float*)d_in[2];
    const float* w_xo = (const float*)d_in[3];
    const float* w_hf = (const float*)d_in[6];
    const float* w_ho = (const float*)d_in[7];
    const float* b_f  = (const float*)d_in[10];
    const float* b_o  = (const float*)d_in[11];
    const float* h0   = (const float*)d_in[13];
    const float* c0   = (const float*)d_in[14];
    float* out = (float*)d_out;

    float* zp     = (float*)d_ws;                  // [1024][1024] fp32 = 4 MB
    float* vbuf   = zp + (size_t)NBLK1 * 1024;     // 2048 fp32
    float* obuf   = vbuf + HS;                     // 2048 fp32
    unsigned* cnt = (unsigned*)(obuf + HS);        // ticket (any init ok)

    gemv_slab<<<NBLK1, 256, 0, stream>>>(x, h0, w_xf, w_hf, w_xo, w_ho, zp);
    reduce_fin<<<NBLK2, 256, 0, stream>>>(zp, b_f, b_o, c0, out, vbuf, obuf, cnt);
}

// Round 9
// 22.676 us; speedup vs baseline: 1.0432x; 1.0432x over previous
//
#include <hip/hip_runtime.h>
#include <math.h>

// Geometry (fixed by the reference).
#define HS    2048            // hidden size (output columns)
#define DIN   2048            // input dim (reduction length)
#define RPS   16              // rows per slab
#define NSLAB (DIN / RPS)     // 128 slabs per matrix
#define NBLK1 512             // 4 mats x 128 slabs; 2 blocks/CU, 1 generation
#define NBLK2 64              // stage-2 blocks

// ---------------------------------------------------------------------------
// Algebra: cell = f*c0 + dot(i,c); dot(i,c) is a scalar broadcast and the
// mean/std normalization cancels constant shifts, so
//   h = o * tanh((f*c0 - mean(f*c0)) / (std(f*c0, ddof=1) + 1e-5)).
// The i and c gates (w_xi, w_hi, w_xc, w_hc, b_i, b_c) are dead.
//
// Stage 1: CONTIGUOUS-slab persistent-ish GEMV. Block b: mat = b>>7,
// slab = b&127 -> rows [slab*16, slab*16+16), FULL 2048-col width: the
// block's stream is one contiguous 128 KB range (16 rows x 8 KB). Thread t
// owns fixed col quads t*4 and 1024+t*4 -> 32 independent float4 loads,
// every wave-instruction 1 KB contiguous. 512 blocks = 2/CU: exactly ONE
// block generation (no churn, no repeated latency ramps, no mid-kernel
// vmcnt(0) drains). 4 rotating float4 accumulators; one coalesced 8 KB
// partial-row store. zp [512][2048] = 4 MB, pure overwrite (poison-proof),
// no atomics, no LDS.
// ---------------------------------------------------------------------------
__global__ __launch_bounds__(256) void gemv_slab(
        const float* __restrict__ x,    const float* __restrict__ h0,
        const float* __restrict__ w_xf, const float* __restrict__ w_hf,
        const float* __restrict__ w_xo, const float* __restrict__ w_ho,
        float* __restrict__ zp /* [NBLK1][HS] */) {
    const int b    = blockIdx.x;
    const int t    = threadIdx.x;
    const int mat  = b >> 7;                 // 0:w_xf 1:w_hf 2:w_xo 3:w_ho
    const int slab = b & (NSLAB - 1);

    const float* W   = (mat == 0) ? w_xf : (mat == 1) ? w_hf
                     : (mat == 2) ? w_xo : w_ho;
    const float* vec = (mat & 1) ? h0 : x;

    const int r0 = slab * RPS;
    const float* wp = W + (size_t)r0 * HS + t * 4;

    float4 a0 = make_float4(0.f, 0.f, 0.f, 0.f);  // quad0, even rows
    float4 a1 = make_float4(0.f, 0.f, 0.f, 0.f);  // quad1, even rows
    float4 a2 = make_float4(0.f, 0.f, 0.f, 0.f);  // quad0, odd rows
    float4 a3 = make_float4(0.f, 0.f, 0.f, 0.f);  // quad1, odd rows
#pragma unroll
    for (int r = 0; r < RPS; r += 2) {
        const float s0 = vec[r0 + r];        // block-uniform -> scalar load
        const float s1 = vec[r0 + r + 1];
        const float4 w00 = *reinterpret_cast<const float4*>(wp + (size_t)r * HS);
        const float4 w01 = *reinterpret_cast<const float4*>(wp + (size_t)r * HS + 1024);
        const float4 w10 = *reinterpret_cast<const float4*>(wp + (size_t)(r + 1) * HS);
        const float4 w11 = *reinterpret_cast<const float4*>(wp + (size_t)(r + 1) * HS + 1024);
        a0.x = fmaf(s0, w00.x, a0.x);  a0.y = fmaf(s0, w00.y, a0.y);
        a0.z = fmaf(s0, w00.z, a0.z);  a0.w = fmaf(s0, w00.w, a0.w);
        a1.x = fmaf(s0, w01.x, a1.x);  a1.y = fmaf(s0, w01.y, a1.y);
        a1.z = fmaf(s0, w01.z, a1.z);  a1.w = fmaf(s0, w01.w, a1.w);
        a2.x = fmaf(s1, w10.x, a2.x);  a2.y = fmaf(s1, w10.y, a2.y);
        a2.z = fmaf(s1, w10.z, a2.z);  a2.w = fmaf(s1, w10.w, a2.w);
        a3.x = fmaf(s1, w11.x, a3.x);  a3.y = fmaf(s1, w11.y, a3.y);
        a3.z = fmaf(s1, w11.z, a3.z);  a3.w = fmaf(s1, w11.w, a3.w);
    }
    float4 q0, q1;
    q0.x = a0.x + a2.x;  q0.y = a0.y + a2.y;
    q0.z = a0.z + a2.z;  q0.w = a0.w + a2.w;
    q1.x = a1.x + a3.x;  q1.y = a1.y + a3.y;
    q1.z = a1.z + a3.z;  q1.w = a1.w + a3.w;
    float4* zrow = reinterpret_cast<float4*>(zp + (size_t)b * HS);
    zrow[t]       = q0;   // cols t*4 ..
    zrow[256 + t] = q1;   // cols 1024 + t*4 ..
}

// ---------------------------------------------------------------------------
// Stage 2: reduce 256 partial rows per gate (zp rows [g*256, g*256+256)),
// float4 loads, sigmoid, then last-block ticket -> mean/std -> output.
//   block bb: gate g = bb>>5, col group cg = bb&31 (64 cols).
//   thread t: fg = t&15 (float4 quad), ph = t>>4 (16 phases); sums rows
//   g*256 + ph + 16k, k=0..15 (16 independent float4 loads, L2/L3-hot).
// vbuf/obuf fully overwritten each call; atomicInc-wrap ticket selects
// exactly one block per call for ANY initial counter value (0xAA poison ok).
// ---------------------------------------------------------------------------
__global__ __launch_bounds__(256) void reduce_fin(
        const float* __restrict__ zp,
        const float* __restrict__ b_f, const float* __restrict__ b_o,
        const float* __restrict__ c0,  float* __restrict__ out,
        float* __restrict__ vbuf, float* __restrict__ obuf,
        unsigned* __restrict__ cnt) {
    const int t  = threadIdx.x;
    const int g  = blockIdx.x >> 5;          // 0 = f, 1 = o
    const int cg = blockIdx.x & 31;          // 64-col group
    const int fg = t & 15;                   // float4 quad within group
    const int ph = t >> 4;                   // row phase 0..15

    __shared__ float4 part[4][16];
    __shared__ unsigned lastFlag;

    const int colq = cg * 64 + fg * 4;       // this thread's column quad

    float4 acc0 = make_float4(0.f, 0.f, 0.f, 0.f);
    float4 acc1 = make_float4(0.f, 0.f, 0.f, 0.f);
#pragma unroll
    for (int k = 0; k < 16; k += 2) {
        const int row0 = g * 256 + ph + (k << 4);
        const int row1 = g * 256 + ph + ((k + 1) << 4);
        const float4 p0 = *reinterpret_cast<const float4*>(
            zp + (size_t)row0 * HS + colq);
        const float4 p1 = *reinterpret_cast<const float4*>(
            zp + (size_t)row1 * HS + colq);
        acc0.x += p0.x;  acc0.y += p0.y;  acc0.z += p0.z;  acc0.w += p0.w;
        acc1.x += p1.x;  acc1.y += p1.y;  acc1.z += p1.z;  acc1.w += p1.w;
    }
    float4 s4;
    s4.x = acc0.x + acc1.x;  s4.y = acc0.y + acc1.y;
    s4.z = acc0.z + acc1.z;  s4.w = acc0.w + acc1.w;

    // reduce the 4 in-wave phases (lane l, l^16, l^32 hold adjacent ph)
#pragma unroll
    for (int m = 16; m <= 32; m <<= 1) {
        s4.x += __shfl_xor(s4.x, m);
        s4.y += __shfl_xor(s4.y, m);
        s4.z += __shfl_xor(s4.z, m);
        s4.w += __shfl_xor(s4.w, m);
    }
    if ((t & 63) < 16) part[t >> 6][fg] = s4;
    __syncthreads();

    if (t < 16) {
        float4 z;
        z.x = (part[0][t].x + part[1][t].x) + (part[2][t].x + part[3][t].x);
        z.y = (part[0][t].y + part[1][t].y) + (part[2][t].y + part[3][t].y);
        z.z = (part[0][t].z + part[1][t].z) + (part[2][t].z + part[3][t].z);
        z.w = (part[0][t].w + part[1][t].w) + (part[2][t].w + part[3][t].w);
        const int col = cg * 64 + t * 4;
        if (g == 0) {
            const float4 bf = *reinterpret_cast<const float4*>(b_f + col);
            const float4 cv = *reinterpret_cast<const float4*>(c0 + col);
            float4 r;
            r.x = cv.x / (1.f + expf(-(z.x + bf.x)));
            r.y = cv.y / (1.f + expf(-(z.y + bf.y)));
            r.z = cv.z / (1.f + expf(-(z.z + bf.z)));
            r.w = cv.w / (1.f + expf(-(z.w + bf.w)));
            *reinterpret_cast<float4*>(vbuf + col) = r;   // v = sig(zf)*c0
        } else {
            const float4 bo = *reinterpret_cast<const float4*>(b_o + col);
            float4 r;
            r.x = 1.f / (1.f + expf(-(z.x + bo.x)));
            r.y = 1.f / (1.f + expf(-(z.y + bo.y)));
            r.z = 1.f / (1.f + expf(-(z.z + bo.z)));
            r.w = 1.f / (1.f + expf(-(z.w + bo.w)));
            *reinterpret_cast<float4*>(obuf + col) = r;   // o gate
        }
    }
    __syncthreads();

    // ---- last-block ticket (device scope; robust to any initial cnt) ----
    if (t == 0) {
        __threadfence();                          // release vbuf/obuf writes
        const unsigned old = atomicInc(cnt, NBLK2 - 1u);
        lastFlag = (old == NBLK2 - 2u);           // exactly one block per call
    }
    __syncthreads();
    if (!lastFlag) return;
    __threadfence();                              // acquire

    // ---- finalize: h = o * tanh((v - mean) / (std_ddof1 + 1e-5)) ----
    const int lane = t & 63;
    const int wv   = t >> 6;
    __shared__ float red[2][4];

    float v[8], og[8];
    float lsum = 0.f;
#pragma unroll
    for (int e = 0; e < 8; ++e) {
        const int j = t * 8 + e;
        v[e]  = vbuf[j];
        og[e] = obuf[j];
        lsum += v[e];
    }
#pragma unroll
    for (int s = 32; s > 0; s >>= 1) lsum += __shfl_down(lsum, s);
    if (lane == 0) red[0][wv] = lsum;
    __syncthreads();
    const float mean = (red[0][0] + red[0][1] + red[0][2] + red[0][3]) * (1.f / 2048.f);

    float lss = 0.f;
#pragma unroll
    for (int e = 0; e < 8; ++e) {
        const float d = v[e] - mean;
        lss += d * d;
    }
#pragma unroll
    for (int s = 32; s > 0; s >>= 1) lss += __shfl_down(lss, s);
    if (lane == 0) red[1][wv] = lss;
    __syncthreads();
    const float var = (red[1][0] + red[1][1] + red[1][2] + red[1][3]) * (1.f / 2047.f);
    const float inv = 1.f / (sqrtf(var) + 1e-5f);

#pragma unroll
    for (int e = 0; e < 8; ++e) {
        const int j = t * 8 + e;
        out[j] = og[e] * tanhf((v[e] - mean) * inv);
    }
}

extern "C" void kernel_launch(void* const* d_in, const int* in_sizes, int n_in,
                              void* d_out, int out_size, void* d_ws, size_t ws_size,
                              hipStream_t stream) {
    // setup_inputs order:
    // 0:x 1:w_xi 2:w_xf 3:w_xo 4:w_xc 5:w_hi 6:w_hf 7:w_ho 8:w_hc
    // 9:b_i 10:b_f 11:b_o 12:b_c 13:h0 14:c0
    const float* x    = (const float*)d_in[0];
    const float* w_xf = (const float*)d_in[2];
    const float* w_xo = (const float*)d_in[3];
    const float* w_hf = (const float*)d_in[6];
    const float* w_ho = (const float*)d_in[7];
    const float* b_f  = (const float*)d_in[10];
    const float* b_o  = (const float*)d_in[11];
    const float* h0   = (const float*)d_in[13];
    const float* c0   = (const float*)d_in[14];
    float* out = (float*)d_out;

    float* zp     = (float*)d_ws;                  // [512][2048] fp32 = 4 MB
    float* vbuf   = zp + (size_t)NBLK1 * HS;       // 2048 fp32
    float* obuf   = vbuf + HS;                     // 2048 fp32
    unsigned* cnt = (unsigned*)(obuf + HS);        // ticket (any init ok)

    gemv_slab<<<NBLK1, 256, 0, stream>>>(x, h0, w_xf, w_hf, w_xo, w_ho, zp);
    reduce_fin<<<NBLK2, 256, 0, stream>>>(zp, b_f, b_o, c0, out, vbuf, obuf, cnt);
}

// Round 11
// 22.060 us; speedup vs baseline: 1.0724x; 1.0279x over previous
//
#include <hip/hip_runtime.h>
#include <math.h>

// Geometry (fixed by the reference).
#define HS    2048            // hidden size (output columns)
#define DIN   2048            // input dim (reduction length)
#define RPS   16              // rows per slab
#define NSLAB (DIN / RPS)     // 128 slabs per matrix
#define NBLK1 512             // 4 mats x 128 slabs; 2 blocks/CU, 1 generation
#define NBLK2 64              // stage-2 blocks

// Native Clang vector type: __builtin_nontemporal_load accepts these
// (it rejects HIP_vector_type<float,4>*).
typedef float float4n __attribute__((ext_vector_type(4)));

// ---------------------------------------------------------------------------
// Algebra: cell = f*c0 + dot(i,c); dot(i,c) is a scalar broadcast and the
// mean/std normalization cancels constant shifts, so
//   h = o * tanh((f*c0 - mean(f*c0)) / (std(f*c0, ddof=1) + 1e-5)).
// The i and c gates (w_xi, w_hi, w_xc, w_hc, b_i, b_c) are dead.
//
// Stage 1 = r9's contiguous-slab GEMV with ONE change: weight loads are
// NON-TEMPORAL (nt cache flag) — the 64 MB weight stream is single-use, so
// skip cache allocation (no 32 MB L2 evict-and-fill churn). Everything else
// identical to r9: block b: mat = b>>7, slab = b&127, contiguous 128 KB
// stream (16 rows x 8 KB), thread t owns col quads t*4 and 1024+t*4, 32
// independent float4 loads, 4 rotating accumulators, one coalesced 8 KB
// partial-row store. zp [512][2048] = 4 MB, pure overwrite (poison-proof),
// no atomics, no LDS.
// ---------------------------------------------------------------------------
__global__ __launch_bounds__(256) void gemv_slab(
        const float* __restrict__ x,    const float* __restrict__ h0,
        const float* __restrict__ w_xf, const float* __restrict__ w_hf,
        const float* __restrict__ w_xo, const float* __restrict__ w_ho,
        float* __restrict__ zp /* [NBLK1][HS] */) {
    const int b    = blockIdx.x;
    const int t    = threadIdx.x;
    const int mat  = b >> 7;                 // 0:w_xf 1:w_hf 2:w_xo 3:w_ho
    const int slab = b & (NSLAB - 1);

    const float* W   = (mat == 0) ? w_xf : (mat == 1) ? w_hf
                     : (mat == 2) ? w_xo : w_ho;
    const float* vec = (mat & 1) ? h0 : x;

    const int r0 = slab * RPS;
    const float4n* wp = reinterpret_cast<const float4n*>(W + (size_t)r0 * HS) + t;

    float4n a0 = {0.f, 0.f, 0.f, 0.f};  // quad0, even rows
    float4n a1 = {0.f, 0.f, 0.f, 0.f};  // quad1, even rows
    float4n a2 = {0.f, 0.f, 0.f, 0.f};  // quad0, odd rows
    float4n a3 = {0.f, 0.f, 0.f, 0.f};  // quad1, odd rows
#pragma unroll
    for (int r = 0; r < RPS; r += 2) {
        const float s0 = vec[r0 + r];        // block-uniform -> scalar load
        const float s1 = vec[r0 + r + 1];
        // non-temporal: single-use stream, bypass cache allocation
        const float4n w00 = __builtin_nontemporal_load(wp + (size_t)r * (HS / 4));
        const float4n w01 = __builtin_nontemporal_load(wp + (size_t)r * (HS / 4) + 256);
        const float4n w10 = __builtin_nontemporal_load(wp + (size_t)(r + 1) * (HS / 4));
        const float4n w11 = __builtin_nontemporal_load(wp + (size_t)(r + 1) * (HS / 4) + 256);
        a0 += s0 * w00;
        a1 += s0 * w01;
        a2 += s1 * w10;
        a3 += s1 * w11;
    }
    const float4n q0 = a0 + a2;
    const float4n q1 = a1 + a3;
    float4n* zrow = reinterpret_cast<float4n*>(zp + (size_t)b * HS);
    zrow[t]       = q0;   // cols t*4 ..
    zrow[256 + t] = q1;   // cols 1024 + t*4 ..
}

// ---------------------------------------------------------------------------
// Stage 2 (unchanged from r9): reduce 256 partial rows per gate, float4
// loads, sigmoid, then last-block ticket -> mean/std -> output.
// atomicInc-wrap ticket selects exactly one block per call for ANY initial
// counter value (0xAA poison ok).
// ---------------------------------------------------------------------------
__global__ __launch_bounds__(256) void reduce_fin(
        const float* __restrict__ zp,
        const float* __restrict__ b_f, const float* __restrict__ b_o,
        const float* __restrict__ c0,  float* __restrict__ out,
        float* __restrict__ vbuf, float* __restrict__ obuf,
        unsigned* __restrict__ cnt) {
    const int t  = threadIdx.x;
    const int g  = blockIdx.x >> 5;          // 0 = f, 1 = o
    const int cg = blockIdx.x & 31;          // 64-col group
    const int fg = t & 15;                   // float4 quad within group
    const int ph = t >> 4;                   // row phase 0..15

    __shared__ float4 part[4][16];
    __shared__ unsigned lastFlag;

    const int colq = cg * 64 + fg * 4;       // this thread's column quad

    float4 acc0 = make_float4(0.f, 0.f, 0.f, 0.f);
    float4 acc1 = make_float4(0.f, 0.f, 0.f, 0.f);
#pragma unroll
    for (int k = 0; k < 16; k += 2) {
        const int row0 = g * 256 + ph + (k << 4);
        const int row1 = g * 256 + ph + ((k + 1) << 4);
        const float4 p0 = *reinterpret_cast<const float4*>(
            zp + (size_t)row0 * HS + colq);
        const float4 p1 = *reinterpret_cast<const float4*>(
            zp + (size_t)row1 * HS + colq);
        acc0.x += p0.x;  acc0.y += p0.y;  acc0.z += p0.z;  acc0.w += p0.w;
        acc1.x += p1.x;  acc1.y += p1.y;  acc1.z += p1.z;  acc1.w += p1.w;
    }
    float4 s4;
    s4.x = acc0.x + acc1.x;  s4.y = acc0.y + acc1.y;
    s4.z = acc0.z + acc1.z;  s4.w = acc0.w + acc1.w;

    // reduce the 4 in-wave phases (lane l, l^16, l^32 hold adjacent ph)
#pragma unroll
    for (int m = 16; m <= 32; m <<= 1) {
        s4.x += __shfl_xor(s4.x, m);
        s4.y += __shfl_xor(s4.y, m);
        s4.z += __shfl_xor(s4.z, m);
        s4.w += __shfl_xor(s4.w, m);
    }
    if ((t & 63) < 16) part[t >> 6][fg] = s4;
    __syncthreads();

    if (t < 16) {
        float4 z;
        z.x = (part[0][t].x + part[1][t].x) + (part[2][t].x + part[3][t].x);
        z.y = (part[0][t].y + part[1][t].y) + (part[2][t].y + part[3][t].y);
        z.z = (part[0][t].z + part[1][t].z) + (part[2][t].z + part[3][t].z);
        z.w = (part[0][t].w + part[1][t].w) + (part[2][t].w + part[3][t].w);
        const int col = cg * 64 + t * 4;
        if (g == 0) {
            const float4 bf = *reinterpret_cast<const float4*>(b_f + col);
            const float4 cv = *reinterpret_cast<const float4*>(c0 + col);
            float4 r;
            r.x = cv.x / (1.f + expf(-(z.x + bf.x)));
            r.y = cv.y / (1.f + expf(-(z.y + bf.y)));
            r.z = cv.z / (1.f + expf(-(z.z + bf.z)));
            r.w = cv.w / (1.f + expf(-(z.w + bf.w)));
            *reinterpret_cast<float4*>(vbuf + col) = r;   // v = sig(zf)*c0
        } else {
            const float4 bo = *reinterpret_cast<const float4*>(b_o + col);
            float4 r;
            r.x = 1.f / (1.f + expf(-(z.x + bo.x)));
            r.y = 1.f / (1.f + expf(-(z.y + bo.y)));
            r.z = 1.f / (1.f + expf(-(z.z + bo.z)));
            r.w = 1.f / (1.f + expf(-(z.w + bo.w)));
            *reinterpret_cast<float4*>(obuf + col) = r;   // o gate
        }
    }
    __syncthreads();

    // ---- last-block ticket (device scope; robust to any initial cnt) ----
    if (t == 0) {
        __threadfence();                          // release vbuf/obuf writes
        const unsigned old = atomicInc(cnt, NBLK2 - 1u);
        lastFlag = (old == NBLK2 - 2u);           // exactly one block per call
    }
    __syncthreads();
    if (!lastFlag) return;
    __threadfence();                              // acquire

    // ---- finalize: h = o * tanh((v - mean) / (std_ddof1 + 1e-5)) ----
    const int lane = t & 63;
    const int wv   = t >> 6;
    __shared__ float red[2][4];

    float v[8], og[8];
    float lsum = 0.f;
#pragma unroll
    for (int e = 0; e < 8; ++e) {
        const int j = t * 8 + e;
        v[e]  = vbuf[j];
        og[e] = obuf[j];
        lsum += v[e];
    }
#pragma unroll
    for (int s = 32; s > 0; s >>= 1) lsum += __shfl_down(lsum, s);
    if (lane == 0) red[0][wv] = lsum;
    __syncthreads();
    const float mean = (red[0][0] + red[0][1] + red[0][2] + red[0][3]) * (1.f / 2048.f);

    float lss = 0.f;
#pragma unroll
    for (int e = 0; e < 8; ++e) {
        const float d = v[e] - mean;
        lss += d * d;
    }
#pragma unroll
    for (int s = 32; s > 0; s >>= 1) lss += __shfl_down(lss, s);
    if (lane == 0) red[1][wv] = lss;
    __syncthreads();
    const float var = (red[1][0] + red[1][1] + red[1][2] + red[1][3]) * (1.f / 2047.f);
    const float inv = 1.f / (sqrtf(var) + 1e-5f);

#pragma unroll
    for (int e = 0; e < 8; ++e) {
        const int j = t * 8 + e;
        out[j] = og[e] * tanhf((v[e] - mean) * inv);
    }
}

extern "C" void kernel_launch(void* const* d_in, const int* in_sizes, int n_in,
                              void* d_out, int out_size, void* d_ws, size_t ws_size,
                              hipStream_t stream) {
    // setup_inputs order:
    // 0:x 1:w_xi 2:w_xf 3:w_xo 4:w_xc 5:w_hi 6:w_hf 7:w_ho 8:w_hc
    // 9:b_i 10:b_f 11:b_o 12:b_c 13:h0 14:c0
    const float* x    = (const float*)d_in[0];
    const float* w_xf = (const float*)d_in[2];
    const float* w_xo = (const float*)d_in[3];
    const float* w_hf = (const float*)d_in[6];
    const float* w_ho = (const float*)d_in[7];
    const float* b_f  = (const float*)d_in[10];
    const float* b_o  = (const float*)d_in[11];
    const float* h0   = (const float*)d_in[13];
    const float* c0   = (const float*)d_in[14];
    float* out = (float*)d_out;

    float* zp     = (float*)d_ws;                  // [512][2048] fp32 = 4 MB
    float* vbuf   = zp + (size_t)NBLK1 * HS;       // 2048 fp32
    float* obuf   = vbuf + HS;                     // 2048 fp32
    unsigned* cnt = (unsigned*)(obuf + HS);        // ticket (any init ok)

    gemv_slab<<<NBLK1, 256, 0, stream>>>(x, h0, w_xf, w_hf, w_xo, w_ho, zp);
    reduce_fin<<<NBLK2, 256, 0, stream>>>(zp, b_f, b_o, c0, out, vbuf, obuf, cnt);
}

// Round 12
// 20.899 us; speedup vs baseline: 1.1319x; 1.0556x over previous
//
#include <hip/hip_runtime.h>
#include <math.h>

// Geometry (fixed by the reference).
#define HS    2048            // hidden size (output columns)
#define DIN   2048            // input dim (reduction length)
#define RPS   32              // rows per slab
#define NSLAB (DIN / RPS)     // 64 slabs per matrix
#define NBLK1 256             // 4 mats x 64 slabs; 1 block/CU, 1 generation
#define NBLK2 64              // stage-2 blocks

// Native Clang vector type: __builtin_nontemporal_load accepts these
// (it rejects HIP_vector_type<float,4>*).
typedef float float4n __attribute__((ext_vector_type(4)));

// ---------------------------------------------------------------------------
// Algebra: cell = f*c0 + dot(i,c); dot(i,c) is a scalar broadcast and the
// mean/std normalization cancels constant shifts, so
//   h = o * tanh((f*c0 - mean(f*c0)) / (std(f*c0, ddof=1) + 1e-5)).
// The i and c gates (w_xi, w_hi, w_xc, w_hc, b_i, b_c) are dead.
//
// Stage 1: contiguous-slab GEMV, RPS=32 (halves partial traffic vs r11).
// Block b: mat = b>>6, slab = b&63 -> rows [slab*32, slab*32+32), full
// 2048-col width: one contiguous 256 KB stream per block. Thread t owns
// fixed col quads t*4 and 1024+t*4 -> 64 independent nt float4 loads,
// every wave-instruction 1 KB contiguous. 256 blocks = 1/CU, single
// generation. 4 rotating accumulators; one coalesced 8 KB partial-row
// store. zp [256][2048] = 2 MB, pure overwrite (poison-proof), no atomics,
// no LDS.
// ---------------------------------------------------------------------------
__global__ __launch_bounds__(256) void gemv_slab(
        const float* __restrict__ x,    const float* __restrict__ h0,
        const float* __restrict__ w_xf, const float* __restrict__ w_hf,
        const float* __restrict__ w_xo, const float* __restrict__ w_ho,
        float* __restrict__ zp /* [NBLK1][HS] */) {
    const int b    = blockIdx.x;
    const int t    = threadIdx.x;
    const int mat  = b >> 6;                 // 0:w_xf 1:w_hf 2:w_xo 3:w_ho
    const int slab = b & (NSLAB - 1);

    const float* W   = (mat == 0) ? w_xf : (mat == 1) ? w_hf
                     : (mat == 2) ? w_xo : w_ho;
    const float* vec = (mat & 1) ? h0 : x;

    const int r0 = slab * RPS;
    const float4n* wp = reinterpret_cast<const float4n*>(W + (size_t)r0 * HS) + t;

    float4n a0 = {0.f, 0.f, 0.f, 0.f};  // quad0, even rows
    float4n a1 = {0.f, 0.f, 0.f, 0.f};  // quad1, even rows
    float4n a2 = {0.f, 0.f, 0.f, 0.f};  // quad0, odd rows
    float4n a3 = {0.f, 0.f, 0.f, 0.f};  // quad1, odd rows
#pragma unroll
    for (int r = 0; r < RPS; r += 2) {
        const float s0 = vec[r0 + r];        // block-uniform -> scalar load
        const float s1 = vec[r0 + r + 1];
        // non-temporal: single-use stream, bypass cache allocation
        const float4n w00 = __builtin_nontemporal_load(wp + (size_t)r * (HS / 4));
        const float4n w01 = __builtin_nontemporal_load(wp + (size_t)r * (HS / 4) + 256);
        const float4n w10 = __builtin_nontemporal_load(wp + (size_t)(r + 1) * (HS / 4));
        const float4n w11 = __builtin_nontemporal_load(wp + (size_t)(r + 1) * (HS / 4) + 256);
        a0 += s0 * w00;
        a1 += s0 * w01;
        a2 += s1 * w10;
        a3 += s1 * w11;
    }
    const float4n q0 = a0 + a2;
    const float4n q1 = a1 + a3;
    float4n* zrow = reinterpret_cast<float4n*>(zp + (size_t)b * HS);
    zrow[t]       = q0;   // cols t*4 ..
    zrow[256 + t] = q1;   // cols 1024 + t*4 ..
}

// ---------------------------------------------------------------------------
// Stage 2: reduce 128 partial rows per gate (zp rows [g*128, g*128+128)),
// float4 loads, sigmoid, then last-block ticket -> mean/std -> output.
//   block bb: gate g = bb>>5, col group cg = bb&31 (64 cols).
//   thread t: fg = t&15 (float4 quad), ph = t>>4 (16 phases); sums rows
//   g*128 + ph + 16k, k=0..7 (8 independent float4 loads, L2-hot 2 MB).
// vbuf/obuf fully overwritten each call; atomicInc-wrap ticket selects
// exactly one block per call for ANY initial counter value (0xAA poison ok).
// ---------------------------------------------------------------------------
__global__ __launch_bounds__(256) void reduce_fin(
        const float* __restrict__ zp,
        const float* __restrict__ b_f, const float* __restrict__ b_o,
        const float* __restrict__ c0,  float* __restrict__ out,
        float* __restrict__ vbuf, float* __restrict__ obuf,
        unsigned* __restrict__ cnt) {
    const int t  = threadIdx.x;
    const int g  = blockIdx.x >> 5;          // 0 = f, 1 = o
    const int cg = blockIdx.x & 31;          // 64-col group
    const int fg = t & 15;                   // float4 quad within group
    const int ph = t >> 4;                   // row phase 0..15

    __shared__ float4 part[4][16];
    __shared__ unsigned lastFlag;

    const int colq = cg * 64 + fg * 4;       // this thread's column quad

    float4 acc0 = make_float4(0.f, 0.f, 0.f, 0.f);
    float4 acc1 = make_float4(0.f, 0.f, 0.f, 0.f);
#pragma unroll
    for (int k = 0; k < 8; k += 2) {
        const int row0 = g * 128 + ph + (k << 4);
        const int row1 = g * 128 + ph + ((k + 1) << 4);
        const float4 p0 = *reinterpret_cast<const float4*>(
            zp + (size_t)row0 * HS + colq);
        const float4 p1 = *reinterpret_cast<const float4*>(
            zp + (size_t)row1 * HS + colq);
        acc0.x += p0.x;  acc0.y += p0.y;  acc0.z += p0.z;  acc0.w += p0.w;
        acc1.x += p1.x;  acc1.y += p1.y;  acc1.z += p1.z;  acc1.w += p1.w;
    }
    float4 s4;
    s4.x = acc0.x + acc1.x;  s4.y = acc0.y + acc1.y;
    s4.z = acc0.z + acc1.z;  s4.w = acc0.w + acc1.w;

    // reduce the 4 in-wave phases (lane l, l^16, l^32 hold adjacent ph)
#pragma unroll
    for (int m = 16; m <= 32; m <<= 1) {
        s4.x += __shfl_xor(s4.x, m);
        s4.y += __shfl_xor(s4.y, m);
        s4.z += __shfl_xor(s4.z, m);
        s4.w += __shfl_xor(s4.w, m);
    }
    if ((t & 63) < 16) part[t >> 6][fg] = s4;
    __syncthreads();

    if (t < 16) {
        float4 z;
        z.x = (part[0][t].x + part[1][t].x) + (part[2][t].x + part[3][t].x);
        z.y = (part[0][t].y + part[1][t].y) + (part[2][t].y + part[3][t].y);
        z.z = (part[0][t].z + part[1][t].z) + (part[2][t].z + part[3][t].z);
        z.w = (part[0][t].w + part[1][t].w) + (part[2][t].w + part[3][t].w);
        const int col = cg * 64 + t * 4;
        if (g == 0) {
            const float4 bf = *reinterpret_cast<const float4*>(b_f + col);
            const float4 cv = *reinterpret_cast<const float4*>(c0 + col);
            float4 r;
            r.x = cv.x / (1.f + expf(-(z.x + bf.x)));
            r.y = cv.y / (1.f + expf(-(z.y + bf.y)));
            r.z = cv.z / (1.f + expf(-(z.z + bf.z)));
            r.w = cv.w / (1.f + expf(-(z.w + bf.w)));
            *reinterpret_cast<float4*>(vbuf + col) = r;   // v = sig(zf)*c0
        } else {
            const float4 bo = *reinterpret_cast<const float4*>(b_o + col);
            float4 r;
            r.x = 1.f / (1.f + expf(-(z.x + bo.x)));
            r.y = 1.f / (1.f + expf(-(z.y + bo.y)));
            r.z = 1.f / (1.f + expf(-(z.z + bo.z)));
            r.w = 1.f / (1.f + expf(-(z.w + bo.w)));
            *reinterpret_cast<float4*>(obuf + col) = r;   // o gate
        }
    }
    __syncthreads();

    // ---- last-block ticket (device scope; robust to any initial cnt) ----
    if (t == 0) {
        __threadfence();                          // release vbuf/obuf writes
        const unsigned old = atomicInc(cnt, NBLK2 - 1u);
        lastFlag = (old == NBLK2 - 2u);           // exactly one block per call
    }
    __syncthreads();
    if (!lastFlag) return;
    __threadfence();                              // acquire

    // ---- finalize: h = o * tanh((v - mean) / (std_ddof1 + 1e-5)) ----
    const int lane = t & 63;
    const int wv   = t >> 6;
    __shared__ float red[2][4];

    float v[8], og[8];
    float lsum = 0.f;
#pragma unroll
    for (int e = 0; e < 8; ++e) {
        const int j = t * 8 + e;
        v[e]  = vbuf[j];
        og[e] = obuf[j];
        lsum += v[e];
    }
#pragma unroll
    for (int s = 32; s > 0; s >>= 1) lsum += __shfl_down(lsum, s);
    if (lane == 0) red[0][wv] = lsum;
    __syncthreads();
    const float mean = (red[0][0] + red[0][1] + red[0][2] + red[0][3]) * (1.f / 2048.f);

    float lss = 0.f;
#pragma unroll
    for (int e = 0; e < 8; ++e) {
        const float d = v[e] - mean;
        lss += d * d;
    }
#pragma unroll
    for (int s = 32; s > 0; s >>= 1) lss += __shfl_down(lss, s);
    if (lane == 0) red[1][wv] = lss;
    __syncthreads();
    const float var = (red[1][0] + red[1][1] + red[1][2] + red[1][3]) * (1.f / 2047.f);
    const float inv = 1.f / (sqrtf(var) + 1e-5f);

#pragma unroll
    for (int e = 0; e < 8; ++e) {
        const int j = t * 8 + e;
        out[j] = og[e] * tanhf((v[e] - mean) * inv);
    }
}

extern "C" void kernel_launch(void* const* d_in, const int* in_sizes, int n_in,
                              void* d_out, int out_size, void* d_ws, size_t ws_size,
                              hipStream_t stream) {
    // setup_inputs order:
    // 0:x 1:w_xi 2:w_xf 3:w_xo 4:w_xc 5:w_hi 6:w_hf 7:w_ho 8:w_hc
    // 9:b_i 10:b_f 11:b_o 12:b_c 13:h0 14:c0
    const float* x    = (const float*)d_in[0];
    const float* w_xf = (const float*)d_in[2];
    const float* w_xo = (const float*)d_in[3];
    const float* w_hf = (const float*)d_in[6];
    const float* w_ho = (const float*)d_in[7];
    const float* b_f  = (const float*)d_in[10];
    const float* b_o  = (const float*)d_in[11];
    const float* h0   = (const float*)d_in[13];
    const float* c0   = (const float*)d_in[14];
    float* out = (float*)d_out;

    float* zp     = (float*)d_ws;                  // [256][2048] fp32 = 2 MB
    float* vbuf   = zp + (size_t)NBLK1 * HS;       // 2048 fp32
    float* obuf   = vbuf + HS;                     // 2048 fp32
    unsigned* cnt = (unsigned*)(obuf + HS);        // ticket (any init ok)

    gemv_slab<<<NBLK1, 256, 0, stream>>>(x, h0, w_xf, w_hf, w_xo, w_ho, zp);
    reduce_fin<<<NBLK2, 256, 0, stream>>>(zp, b_f, b_o, c0, out, vbuf, obuf, cnt);
}